// Round 9
// baseline (199.062 us; speedup 1.0000x reference)
//
#include <hip/hip_runtime.h>
#include <math.h>

typedef __bf16 bf16x8 __attribute__((ext_vector_type(8)));
typedef float f32x16 __attribute__((ext_vector_type(16)));

#define NTOK 131072
#define HDIM 128
#define ODIM 128
#define NEXP 8
// K padded to 9 kt-steps of 16: kt 0..7 = real H, kt 8 = bias row (x side = 1.0)

__device__ __forceinline__ unsigned short f2bf(float f){
  union { float f; unsigned u; } v; v.f = f;
  unsigned r = v.u + 0x7FFFu + ((v.u >> 16) & 1u);
  return (unsigned short)(r >> 16);
}

// ---------------------------------------------------------------------------
// Kernel 1: pack W into A-operand fragment layout (transposed GEMM: A[m=o][k=h])
// pw flat: [e][mt(4)][kt(9)][lane(64)][j(8)] bf16
// A-frag (v_mfma_f32_32x32x16_bf16): A[m=lane&31][k=(lane>>5)*8+j]
// kt==8: k-local 0 row = b_expert[e][o], rest zero.
__global__ void pack_w(const float* __restrict__ we, const float* __restrict__ be,
                       unsigned short* __restrict__ pw){
  int f = blockIdx.x * 256 + threadIdx.x;      // 0..18431
  int l  = f & 63;
  int kt = (f >> 6) % 9;
  int emt = f / (64 * 9);
  int mt = emt & 3;
  int e  = emt >> 2;
  int o  = (mt << 5) + (l & 31);
  unsigned short vals[8];
#pragma unroll
  for (int j = 0; j < 8; ++j){
    int kl = ((l >> 5) << 3) + j;
    float v;
    if (kt < 8){
      int h = kt * 16 + kl;
      v = we[(e * HDIM + h) * ODIM + o];
    } else {
      v = (kl == 0) ? be[e * ODIM + o] : 0.0f;
    }
    vals[j] = f2bf(v);
  }
  *(bf16x8*)(pw + (size_t)f * 8) = *(bf16x8*)vals;
}

// ---------------------------------------------------------------------------
// Kernel 2: FUSED gating + MoE FFN. R12 (phase-collapse round): the ledger
// (R6 63.4 / R8 62.9 / R10 64.0 / R11 69.4 — 4 structures within 2%) killed
// the occupancy, LDS-pipe, L2-traffic, and chain-ILP theories. Pipe totals
// at 62.9: MFMA 15.5 (AT its dense-work floor: MfmaUtil 24% == 15.5/62.9),
// VALU ~13, HBM ~16, L2 ~17 — sum ~= dur: pipes SERIALIZED by the invariant
// 6-barrier phase skeleton (stage->gate->top2(serial)->build->eloop->
// transpose). This round collapses it to ONE barrier, zero serial sections:
//  1. x -> regs DIRECTLY in frag order (thread t: token t>>2, h-slice
//     (t&3)*32; same values the xs round-trip produced). No stage phase.
//  2. f32 gating from those regs: 8 partial logits over own h-slice (wg rows
//     from global, 4KB L1-hot), 2x shfl_xor reduce (token-mates are adjacent
//     lanes; commutative-exact, all lanes identical), in-lane top2+softmax
//     (redundant x4, no wave0 phase). Sum-order delta ~1e-7 on logits with
//     ~0.3 spread: no top-k flip risk beyond what we already carry vs jax.
//  3. frag build unchanged -> ONE __syncthreads (frags + gates).
//  4. e-loop = R6 verbatim (LDS b-frags, transient a, interleaved p0/p1).
//  5. DIRECT float4 stores (C rr-contiguous in o) — transpose+2 barriers gone
//     (R9 proved direct stores correct; its regression was pk_mul).
// LDS 39.9 -> 20.5 KB. Spill tripwire: WRITE_SIZE exactly 65536 KB.
// CRITICAL (R1-R3): accumulators NAMED / constant-indexed only.
__launch_bounds__(256, 3)
__global__ void moe_fused(const float* __restrict__ x, const float* __restrict__ wg,
                          const unsigned short* __restrict__ pw, float* __restrict__ out){
  __shared__ char lds[18432 + 2048];
  unsigned short* frag = (unsigned short*)lds;        // [tg2][kt9][l64][j8] bf16
  float* glds          = (float*)(lds + 18432);       // [e8][tok64] f32 gates

  int t = threadIdx.x;
  size_t tokbase = (size_t)blockIdx.x * 64;

  // --- x -> regs, frag-build order. thread t: token tok = t>>2, q = t&3,
  // h = q*32 .. q*32+31. 8 contiguous float4 (128B aligned).
  int tokL = t >> 2, q = t & 3;
  const float4* xr = (const float4*)(x + (tokbase + tokL) * HDIM + q * 32);
  float4 cv[8];
#pragma unroll
  for (int i = 0; i < 8; ++i) cv[i] = xr[i];

  // --- gating, fully parallel. Partial logits over own 32-h slice, all 8 e.
  // wg[h][e] rows read directly from global (4KB total, L1-hot after warmup).
  float p[8];
#pragma unroll
  for (int e = 0; e < 8; ++e) p[e] = 0.0f;
#pragma unroll
  for (int i = 0; i < 8; ++i){
    int hb = q * 32 + i * 4;                 // 4 h-rows per cv[i]
    float4 w0a = *(const float4*)(wg + (hb + 0) * 8);
    float4 w0b = *(const float4*)(wg + (hb + 0) * 8 + 4);
    float4 w1a = *(const float4*)(wg + (hb + 1) * 8);
    float4 w1b = *(const float4*)(wg + (hb + 1) * 8 + 4);
    float4 w2a = *(const float4*)(wg + (hb + 2) * 8);
    float4 w2b = *(const float4*)(wg + (hb + 2) * 8 + 4);
    float4 w3a = *(const float4*)(wg + (hb + 3) * 8);
    float4 w3b = *(const float4*)(wg + (hb + 3) * 8 + 4);
    float4 v = cv[i];
    p[0] += v.x * w0a.x + v.y * w1a.x + v.z * w2a.x + v.w * w3a.x;
    p[1] += v.x * w0a.y + v.y * w1a.y + v.z * w2a.y + v.w * w3a.y;
    p[2] += v.x * w0a.z + v.y * w1a.z + v.z * w2a.z + v.w * w3a.z;
    p[3] += v.x * w0a.w + v.y * w1a.w + v.z * w2a.w + v.w * w3a.w;
    p[4] += v.x * w0b.x + v.y * w1b.x + v.z * w2b.x + v.w * w3b.x;
    p[5] += v.x * w0b.y + v.y * w1b.y + v.z * w2b.y + v.w * w3b.y;
    p[6] += v.x * w0b.z + v.y * w1b.z + v.z * w2b.z + v.w * w3b.z;
    p[7] += v.x * w0b.w + v.y * w1b.w + v.z * w2b.w + v.w * w3b.w;
  }
  // cross-q reduce: token-mates are lanes {4k..4k+3}. Commutative-exact ->
  // all 4 lanes end with bit-identical full logits.
#pragma unroll
  for (int e = 0; e < 8; ++e){
    p[e] += __shfl_xor(p[e], 1);
    p[e] += __shfl_xor(p[e], 2);
  }
  // top-2 (ties -> lowest index, matches lax.top_k) + softmax, in-lane.
  {
    int i1 = 0; float v1 = p[0];
#pragma unroll
    for (int e = 1; e < 8; ++e) if (p[e] > v1){ v1 = p[e]; i1 = e; }
    int i2 = -1; float v2 = -3.4e38f;
#pragma unroll
    for (int e = 0; e < 8; ++e) if (e != i1 && p[e] > v2){ v2 = p[e]; i2 = e; }
    float ex = __expf(v2 - v1);
    float inv = 1.0f / (1.0f + ex);
    // thread (q) writes experts q and q+4 for its token (full 8-e coverage).
    float gq  = (q     == i1) ? inv : ((q     == i2) ? ex * inv : 0.0f);
    float gq4 = (q + 4 == i1) ? inv : ((q + 4 == i2) ? ex * inv : 0.0f);
    glds[q * 64 + tokL]       = gq;
    glds[(q + 4) * 64 + tokL] = gq4;
  }

  // --- convert cv -> bf16 B-frags in LDS.
  // B-frag: B[k=(lane>>5)*8+j][n=lane&31] = x[token=tg*32+(lane&31)][h=kt*16+k]
  {
    int tg = tokL >> 5;
#pragma unroll
    for (int jb = 0; jb < 4; ++jb){
      int h0 = q * 32 + jb * 8;
      int kt = h0 >> 4;
      int lslot = (tokL & 31) + 32 * ((h0 >> 3) & 1);
      float4 a = cv[2 * jb], b = cv[2 * jb + 1];
      unsigned long long lo = (unsigned long long)f2bf(a.x)
                            | ((unsigned long long)f2bf(a.y) << 16)
                            | ((unsigned long long)f2bf(a.z) << 32)
                            | ((unsigned long long)f2bf(a.w) << 48);
      unsigned long long hi = (unsigned long long)f2bf(b.x)
                            | ((unsigned long long)f2bf(b.y) << 16)
                            | ((unsigned long long)f2bf(b.z) << 32)
                            | ((unsigned long long)f2bf(b.w) << 48);
      unsigned long long* dst =
        (unsigned long long*)&frag[(((tg * 9) + kt) * 64 + lslot) * 8];
      dst[0] = lo; dst[1] = hi;
    }
    // bias kt=8 slots: 128 slots (2 tg x 64 l)
    if (t < 128){
      int btg = t >> 6, bl = t & 63;
      unsigned long long* dst =
        (unsigned long long*)&frag[(((btg * 9) + 8) * 64 + bl) * 8];
      dst[0] = (bl < 32) ? 0x3F80ull : 0ull;   // bf16 1.0 at j==0, k<8 half
      dst[1] = 0ull;
    }
  }
  __syncthreads();   // THE barrier: frags + gates ready

  // --- Phase B: MFMA. C[o][token] = sum_h W[h][o] * x[token][h]
  // R6-form: b-frags from LDS (conflict-free 1KB-contiguous tiles), transient
  // a stream (1 KB/wave contiguous L2), interleaved p0/p1 chains.
  int w = t >> 6, l = t & 63, l32 = l & 31, lh = l >> 5;

  f32x16 zero16;
#pragma unroll
  for (int i = 0; i < 16; ++i) zero16[i] = 0.0f;
  f32x16 tot0 = zero16, tot1 = zero16;

  const bf16x8* pwp = (const bf16x8*)pw;
#pragma unroll 1
  for (int e = 0; e < 8; ++e){
    float g0 = glds[e * 64 + l32];        // 2-way broadcast pair: free
    float g1 = glds[e * 64 + 32 + l32];
    const bf16x8* ap = pwp + ((size_t)(e * 4 + w) * 9) * 64 + l;
    f32x16 p0 = zero16, p1 = zero16;
#pragma unroll
    for (int kt = 0; kt < 9; ++kt){
      bf16x8 a  = ap[kt * 64];            // transient: used twice, then dead
      bf16x8 b0 = *(const bf16x8*)&frag[((0 * 9 + kt) * 64 + l) * 8];
      bf16x8 b1 = *(const bf16x8*)&frag[((1 * 9 + kt) * 64 + l) * 8];
      p0 = __builtin_amdgcn_mfma_f32_32x32x16_bf16(a, b0, p0, 0, 0, 0);
      p1 = __builtin_amdgcn_mfma_f32_32x32x16_bf16(a, b1, p1, 0, 0, 0);
    }
#pragma unroll
    for (int r = 0; r < 16; ++r){         // static indices only
      tot0[r] += g0 * p0[r];
      tot1[r] += g1 * p1[r];
    }
  }

  // --- epilogue: DIRECT stores. C/D map: token(col)=l32,
  // o(row) = w*32 + rg*8 + lh*4 + rr — rr 0..3 contiguous in o -> float4.
#pragma unroll
  for (int rg = 0; rg < 4; ++rg){
    int o = w * 32 + rg * 8 + lh * 4;
    *(float4*)(out + (tokbase + l32) * ODIM + o) =
      make_float4(tot0[rg * 4 + 0], tot0[rg * 4 + 1], tot0[rg * 4 + 2], tot0[rg * 4 + 3]);
    *(float4*)(out + (tokbase + 32 + l32) * ODIM + o) =
      make_float4(tot1[rg * 4 + 0], tot1[rg * 4 + 1], tot1[rg * 4 + 2], tot1[rg * 4 + 3]);
  }
}

// ---------------------------------------------------------------------------
extern "C" void kernel_launch(void* const* d_in, const int* in_sizes, int n_in,
                              void* d_out, int out_size, void* d_ws, size_t ws_size,
                              hipStream_t stream){
  const float* x  = (const float*)d_in[0];
  const float* wg = (const float*)d_in[1];
  // d_in[2] = w_noise (inactive in eval mode)
  const float* we = (const float*)d_in[3];
  const float* be = (const float*)d_in[4];
  // d_in[5] = top_k (== 2, baked in)
  float* out = (float*)d_out;

  unsigned short* pw = (unsigned short*)d_ws;          // 294,912 B

  pack_w   <<<72,   256, 0, stream>>>(we, be, pw);
  moe_fused<<<2048, 256, 0, stream>>>(x, wg, pw, out);
}